// Round 1
// baseline (240.314 us; speedup 1.0000x reference)
//
#include <hip/hip_runtime.h>

#define BH (512*2048)
#define BHA 1048576ull                   // 512*2048 elems (one activation plane)
#define PPLANE (512ull*8192ull)          // elems per partial plane [512][8192]
#define PLANE_BYTES (PPLANE*2ull)        // bf16
#define WT_ELEMS (8ull*2048*2048)        // transposed bf16 weights (8 matrices)
#define AB_ELEMS (2ull*512*2048)         // bf16 activations (inputs + prevstate)
#define LDT 40

typedef __attribute__((ext_vector_type(8))) short short8;
typedef __attribute__((ext_vector_type(4))) float floatx4;
typedef __attribute__((ext_vector_type(2))) unsigned int uint2v;
typedef __attribute__((ext_vector_type(4))) unsigned int uint4v;
typedef __attribute__((ext_vector_type(8))) unsigned short ushort8v;

#define GLOAD_LDS16(g, l) __builtin_amdgcn_global_load_lds( \
    (const __attribute__((address_space(1))) unsigned int*)(g), \
    (__attribute__((address_space(3))) unsigned int*)(l), 16, 0, 0)

// pack two f32 -> two bf16 (round-half-up) in one dword (R2-R4 verified)
__device__ inline unsigned pk2(float a, float b){
    unsigned ua = __builtin_bit_cast(unsigned, a) + 0x8000u;
    unsigned ub = __builtin_bit_cast(unsigned, b) + 0x8000u;
    return __builtin_amdgcn_perm(ub, ua, 0x07060302u);
}
__device__ inline unsigned short f2bf1(float x){
    return (unsigned short)((__builtin_bit_cast(unsigned, x) + 0x8000u) >> 16);
}
__device__ inline float bf2f(unsigned short s){
    return __builtin_bit_cast(float, ((unsigned)s) << 16);
}
__device__ inline int swz(int r, int g){ return r*4 + (g ^ ((r>>1)&3)); }
__device__ inline float fsig(float x){ return __builtin_amdgcn_rcpf(1.f + __expf(-x)); }
__device__ inline float ftanh(float x){ return 2.f*fsig(2.f*x) - 1.f; }

// ---------------------------------------------------------------------------
// Prepass (R5 rewrite: LDS-transpose streamer).
// bid < 2048: one [32k x 512n] fp32 weight panel -> 4 transposed bf16 tiles.
//   Tile layout identical to before: tile ((gate*16+nb)*128 + kt) is
//   [n_loc 0..127][k_loc 0..31] contiguous 8KB; kt<64 = W rows kt*32..,
//   kt>=64 = U rows (kt-64)*32..
//   Phase 1: coalesced float4 row reads (16/thread), pk2 -> LDS [k][n/2] dwords.
//   Phase 2: conflict-free column read + v_perm split -> 128B/thread
//   contiguous global write.
// bid >= 2048: cast inputs (plane 0) / states[0] (plane 1) to bf16 flat.
// ---------------------------------------------------------------------------
__global__ __launch_bounds__(256) void prep(
    const float* __restrict__ inputs, const float* __restrict__ states,
    const float* __restrict__ Wi, const float* __restrict__ Ui,
    const float* __restrict__ Wf, const float* __restrict__ Uf,
    const float* __restrict__ Wg, const float* __restrict__ Ug,
    const float* __restrict__ Wc, const float* __restrict__ Uc,
    unsigned short* __restrict__ Wt, unsigned short* __restrict__ Ab)
{
    __shared__ unsigned lds[32 * 258];     // [k 0..31][dword-col 0..255] + pad
    const int bid = blockIdx.x, t = threadIdx.x;
    if (bid < 2048) {
        const int gate = bid >> 9, r = bid & 511, kt = r & 127, nbg = r >> 7;
        const float* src; int krow;
        if (kt < 64) {
            krow = kt * 32;
            switch (gate){ case 0: src=Wi; break; case 1: src=Wf; break;
                           case 2: src=Wg; break; default: src=Wc; }
        } else {
            krow = (kt - 64) * 32;
            switch (gate){ case 0: src=Ui; break; case 1: src=Uf; break;
                           case 2: src=Ug; break; default: src=Uc; }
        }
        const float* sb = src + (size_t)krow * 2048 + nbg * 512;
        const int f = t & 31, kr = t >> 5;

        // phase 1: 16 coalesced float4 loads per thread
        floatx4 v[16];
        #pragma unroll
        for (int p = 0; p < 4; p++) {
            const float* rp = sb + (size_t)(p*8 + kr) * 2048 + f * 4;
            #pragma unroll
            for (int q = 0; q < 4; q++)
                v[p*4 + q] = *(const floatx4*)(rp + q * 128);
        }
        #pragma unroll
        for (int p = 0; p < 4; p++) {
            const int k = p*8 + kr;
            #pragma unroll
            for (int q = 0; q < 4; q++) {
                unsigned a = pk2(v[p*4+q][0], v[p*4+q][1]);
                unsigned b = pk2(v[p*4+q][2], v[p*4+q][3]);
                // dword-col c holds global cols (2c, 2c+1) as bf16 pair
                *(uint2v*)&lds[k*258 + 2*(f + 32*q)] = (uint2v){a, b};
            }
        }
        __syncthreads();

        // phase 2: thread t owns dword-col t = output rows n0=2t, n0+1
        unsigned d[32];
        #pragma unroll
        for (int k = 0; k < 32; k++) d[k] = lds[k*258 + t];
        unsigned lo[16], hi[16];
        #pragma unroll
        for (int kp = 0; kp < 16; kp++) {
            lo[kp] = __builtin_amdgcn_perm(d[2*kp+1], d[2*kp], 0x05040100u);
            hi[kp] = __builtin_amdgcn_perm(d[2*kp+1], d[2*kp], 0x07060302u);
        }
        const int n0 = t * 2;
        const int nb = nbg * 4 + (n0 >> 7);
        unsigned short* op = Wt + (size_t)((gate*16 + nb)*128 + kt) * 4096
                                + (size_t)(n0 & 127) * 32;
        *(uint4v*)(op)      = (uint4v){lo[0], lo[1], lo[2],  lo[3]};
        *(uint4v*)(op + 8)  = (uint4v){lo[4], lo[5], lo[6],  lo[7]};
        *(uint4v*)(op + 16) = (uint4v){lo[8], lo[9], lo[10], lo[11]};
        *(uint4v*)(op + 24) = (uint4v){lo[12],lo[13],lo[14], lo[15]};
        *(uint4v*)(op + 32) = (uint4v){hi[0], hi[1], hi[2],  hi[3]};
        *(uint4v*)(op + 40) = (uint4v){hi[4], hi[5], hi[6],  hi[7]};
        *(uint4v*)(op + 48) = (uint4v){hi[8], hi[9], hi[10], hi[11]};
        *(uint4v*)(op + 56) = (uint4v){hi[12],hi[13],hi[14], hi[15]};
    } else {
        const size_t off = ((size_t)(bid - 2048) * 256 + t) * 8;
        const float* src = (off < BHA) ? (inputs + off) : (states + (off - BHA));
        floatx4 v0 = *(const floatx4*)src;
        floatx4 v1 = *(const floatx4*)(src + 4);
        uint4v w;
        w.x = pk2(v0[0],v0[1]); w.y = pk2(v0[2],v0[3]);
        w.z = pk2(v1[0],v1[1]); w.w = pk2(v1[2],v1[3]);
        *(uint4v*)(Ab + off) = w;
    }
}

// ---------------------------------------------------------------------------
// Main GEMM (bf16 pre-converted inputs): m97-style K-loop.
// Block 128x128, 4 waves of 64x64 (4x4 x mfma_16x16x32_bf16), BK=32,
// double-buffered LDS filled by global_load_lds width-16, one barrier/iter.
// ---------------------------------------------------------------------------
__global__ __launch_bounds__(256, 4) void gemm_lds(
    const unsigned short* __restrict__ Wt, const unsigned short* __restrict__ Ab,
    unsigned short* __restrict__ P)
{
    __shared__ unsigned short As[2][4096];   // [m 0..127][k 0..31]
    __shared__ unsigned short Bs[2][4096];   // [n 0..127][k 0..31]

    const int t = threadIdx.x, lane = t & 63, wave = t >> 6;
    const int nblk = blockIdx.x, gate = nblk >> 4, nb = nblk & 15;
    const int m0 = blockIdx.y * 128, z = blockIdx.z;

    const unsigned short* Bt = Wt + ((size_t)(gate*16 + nb) * 128 + z*32) * 4096;
    const unsigned short* Abase = Ab + (size_t)(z >> 1) * BHA
                                     + (size_t)m0 * 2048 + (z & 1) * 1024;

    const int i0 = wave * 2, i1 = wave * 2 + 1;   // this wave's two DMA slots
    const unsigned short* ag0 = Abase + (size_t)(i0*16 + (lane>>2)) * 2048 + (lane&3)*8;
    const unsigned short* ag1 = Abase + (size_t)(i1*16 + (lane>>2)) * 2048 + (lane&3)*8;
    const unsigned short* bg0 = Bt + i0*512 + lane*8;
    const unsigned short* bg1 = Bt + i1*512 + lane*8;

    floatx4 acc[4][4];
    #pragma unroll
    for (int i = 0; i < 4; i++)
        #pragma unroll
        for (int j = 0; j < 4; j++)
            acc[i][j] = (floatx4){0.f,0.f,0.f,0.f};

    const int wm = (wave & 1) * 64, wn = (wave >> 1) * 64;
    const int row16 = lane & 15, g4 = lane >> 4;

    // prologue: DMA tile 0 into buf 0
    GLOAD_LDS16(ag0, &As[0][i0*512]);
    GLOAD_LDS16(ag1, &As[0][i1*512]);
    GLOAD_LDS16(bg0, &Bs[0][i0*512]);
    GLOAD_LDS16(bg1, &Bs[0][i1*512]);
    __syncthreads();

    for (int kk = 0; kk < 32; kk++) {
        const int cur = kk & 1;
        if (kk < 31) {                       // DMA next tile into other buffer
            const int nxt = cur ^ 1;
            GLOAD_LDS16(ag0 + (kk+1)*32,   &As[nxt][i0*512]);
            GLOAD_LDS16(ag1 + (kk+1)*32,   &As[nxt][i1*512]);
            GLOAD_LDS16(bg0 + (kk+1)*4096, &Bs[nxt][i0*512]);
            GLOAD_LDS16(bg1 + (kk+1)*4096, &Bs[nxt][i1*512]);
        }
        short8 afr[4], bfr[4];
        #pragma unroll
        for (int mi = 0; mi < 4; mi++)
            afr[mi] = *(const short8*)&As[cur][(wm + mi*16 + row16)*32 + g4*8];
        #pragma unroll
        for (int ni = 0; ni < 4; ni++)
            bfr[ni] = *(const short8*)&Bs[cur][(wn + ni*16 + row16)*32 + g4*8];
        #pragma unroll
        for (int mi = 0; mi < 4; mi++)
            #pragma unroll
            for (int ni = 0; ni < 4; ni++)
                acc[mi][ni] = __builtin_amdgcn_mfma_f32_16x16x32_bf16(
                    afr[mi], bfr[ni], acc[mi][ni], 0, 0, 0);
        __syncthreads();                     // drains DMA (vmcnt) + barrier
    }

    unsigned short* dst = P + (size_t)z * PPLANE;
    const int gbase = gate * 2048 + nb * 128;
    #pragma unroll
    for (int mi = 0; mi < 4; mi++)
        #pragma unroll
        for (int ni = 0; ni < 4; ni++)
            #pragma unroll
            for (int j = 0; j < 4; j++) {
                int row = m0 + wm + mi*16 + g4*4 + j;
                int col = gbase + wn + ni*16 + row16;
                dst[(size_t)row * 8192 + col] = f2bf1(acc[mi][ni][j]);
            }
}

// ---------------------------------------------------------------------------
// Fallback GEMM (R3 version, fused fp32 staging) for small ws_size.
// ---------------------------------------------------------------------------
__global__ __launch_bounds__(256, 2) void gemm_tile(
    const float* __restrict__ inputs, const float* __restrict__ states,
    const float* __restrict__ Wi, const float* __restrict__ Ui,
    const float* __restrict__ Wf, const float* __restrict__ Uf,
    const float* __restrict__ Wg, const float* __restrict__ Ug,
    const float* __restrict__ Wc, const float* __restrict__ Uc,
    unsigned short* __restrict__ P, int KB)
{
    __shared__ uint4v As[2][512];
    __shared__ uint4v Bs[2][512];

    const int t = threadIdx.x;
    const int m0 = blockIdx.y * 128;
    const int z = blockIdx.z;
    const int nblk = blockIdx.x;
    const int gate = nblk >> 4;
    const int c0 = (nblk & 15) * 128;
    const int gk = z * KB;

    const float* Abase; const float* Bsel; int ko;
    if (gk < 2048) {
        Abase = inputs; ko = gk;
        switch (gate){ case 0: Bsel=Wi; break; case 1: Bsel=Wf; break;
                       case 2: Bsel=Wg; break; default: Bsel=Wc; }
    } else {
        Abase = states; ko = gk - 2048;
        switch (gate){ case 0: Bsel=Ui; break; case 1: Bsel=Uf; break;
                       case 2: Bsel=Ug; break; default: Bsel=Uc; }
    }
    const int NIT = KB >> 5;

    const int lane = t & 63, wave = t >> 6;
    const int wm = (wave & 1) * 64, wn = (wave >> 1) * 64;
    const int row16 = lane & 15, g4 = lane >> 4;
    const int ar = t >> 2, ag = t & 3;
    const int bn = t & 127, bg2 = (t >> 7) * 2;

    const float* Ap = Abase + (size_t)(m0 + ar) * 2048 + ko + ag * 8;
    const float* Bp = Bsel + (size_t)ko * 2048 + c0 + bn;

    floatx4 acc[4][4];
    #pragma unroll
    for (int i = 0; i < 4; i++)
        #pragma unroll
        for (int j = 0; j < 4; j++)
            acc[i][j] = (floatx4){0.f,0.f,0.f,0.f};

    floatx4 a0,a1,a2,a3; float b0[8], b1[8];
    a0 = *(const floatx4*)Ap;             a1 = *(const floatx4*)(Ap + 4);
    a2 = *(const floatx4*)(Ap + 64*2048); a3 = *(const floatx4*)(Ap + 64*2048 + 4);
    #pragma unroll
    for (int j = 0; j < 8; j++) b0[j] = Bp[(size_t)(bg2*8 + j) * 2048];
    #pragma unroll
    for (int j = 0; j < 8; j++) b1[j] = Bp[(size_t)(bg2*8 + 8 + j) * 2048];
    {
        uint4v w;
        w.x=pk2(a0[0],a0[1]); w.y=pk2(a0[2],a0[3]); w.z=pk2(a1[0],a1[1]); w.w=pk2(a1[2],a1[3]);
        As[0][swz(ar, ag)] = w;
        w.x=pk2(a2[0],a2[1]); w.y=pk2(a2[2],a2[3]); w.z=pk2(a3[0],a3[1]); w.w=pk2(a3[2],a3[3]);
        As[0][swz(ar+64, ag)] = w;
        w.x=pk2(b0[0],b0[1]); w.y=pk2(b0[2],b0[3]); w.z=pk2(b0[4],b0[5]); w.w=pk2(b0[6],b0[7]);
        Bs[0][swz(bn, bg2)] = w;
        w.x=pk2(b1[0],b1[1]); w.y=pk2(b1[2],b1[3]); w.z=pk2(b1[4],b1[5]); w.w=pk2(b1[6],b1[7]);
        Bs[0][swz(bn, bg2+1)] = w;
    }

    for (int kk = 0; kk < NIT; kk++) {
        __syncthreads();
        const int cur = kk & 1;
        if (kk + 1 < NIT) {
            const float* ap = Ap + (kk+1) * 32;
            a0 = *(const floatx4*)ap;             a1 = *(const floatx4*)(ap + 4);
            a2 = *(const floatx4*)(ap + 64*2048); a3 = *(const floatx4*)(ap + 64*2048 + 4);
            const float* bp = Bp + (size_t)(kk+1) * 32 * 2048;
            #pragma unroll
            for (int j = 0; j < 8; j++) b0[j] = bp[(size_t)(bg2*8 + j) * 2048];
            #pragma unroll
            for (int j = 0; j < 8; j++) b1[j] = bp[(size_t)(bg2*8 + 8 + j) * 2048];
        }
        short8 afr[4], bfr[4];
        #pragma unroll
        for (int mi = 0; mi < 4; mi++)
            afr[mi] = *(const short8*)&As[cur][swz(wm + mi*16 + row16, g4)];
        #pragma unroll
        for (int ni = 0; ni < 4; ni++)
            bfr[ni] = *(const short8*)&Bs[cur][swz(wn + ni*16 + row16, g4)];
        #pragma unroll
        for (int mi = 0; mi < 4; mi++)
            #pragma unroll
            for (int ni = 0; ni < 4; ni++)
                acc[mi][ni] = __builtin_amdgcn_mfma_f32_16x16x32_bf16(
                    afr[mi], bfr[ni], acc[mi][ni], 0, 0, 0);
        if (kk + 1 < NIT) {
            const int nxt = cur ^ 1;
            uint4v w;
            w.x=pk2(a0[0],a0[1]); w.y=pk2(a0[2],a0[3]); w.z=pk2(a1[1-1],a1[1]); w.w=pk2(a1[2],a1[3]);
            w.z=pk2(a1[0],a1[1]);
            As[nxt][swz(ar, ag)] = w;
            w.x=pk2(a2[0],a2[1]); w.y=pk2(a2[2],a2[3]); w.z=pk2(a3[0],a3[1]); w.w=pk2(a3[2],a3[3]);
            As[nxt][swz(ar+64, ag)] = w;
            w.x=pk2(b0[0],b0[1]); w.y=pk2(b0[2],b0[3]); w.z=pk2(b0[4],b0[5]); w.w=pk2(b0[6],b0[7]);
            Bs[nxt][swz(bn, bg2)] = w;
            w.x=pk2(b1[0],b1[1]); w.y=pk2(b1[2],b1[3]); w.z=pk2(b1[4],b1[5]); w.w=pk2(b1[6],b1[7]);
            Bs[nxt][swz(bn, bg2+1)] = w;
        }
    }

    unsigned short* dst = P + (size_t)z * PPLANE;
    const int gbase = gate * 2048 + c0;
    #pragma unroll
    for (int mi = 0; mi < 4; mi++)
        #pragma unroll
        for (int ni = 0; ni < 4; ni++)
            #pragma unroll
            for (int j = 0; j < 4; j++) {
                int row = m0 + wm + mi*16 + g4*4 + j;
                int col = gbase + wn + ni*16 + row16;
                dst[(size_t)row * 8192 + col] = f2bf1(acc[mi][ni][j]);
            }
}

// activations + LSTM combine
__global__ __launch_bounds__(256) void combine_kernel(
    float* __restrict__ out, const unsigned short* __restrict__ P,
    const float* __restrict__ states,
    const float* __restrict__ bi, const float* __restrict__ bfv,
    const float* __restrict__ bg, const float* __restrict__ bc, int nz)
{
    const int idx = (blockIdx.x * 256 + threadIdx.x) * 8;
    const int row = idx >> 11;
    const int h = idx & 2047;
    const size_t base = (size_t)row * 8192 + h;

    float xi[8], xf[8], xg[8], xc[8];
    #pragma unroll
    for (int e = 0; e < 8; e++) {
        xi[e] = bi[h+e]; xf[e] = bfv[h+e]; xg[e] = bg[h+e]; xc[e] = bc[h+e];
    }
    for (int z = 0; z < nz; z++) {
        const unsigned short* Pz = P + (size_t)z * PPLANE;
        ushort8v vi = *(const ushort8v*)&Pz[base];
        ushort8v vf = *(const ushort8v*)&Pz[base + 2048];
        ushort8v vg = *(const ushort8v*)&Pz[base + 4096];
        ushort8v vc = *(const ushort8v*)&Pz[base + 6144];
        #pragma unroll
        for (int e = 0; e < 8; e++) {
            xi[e] += bf2f(vi[e]); xf[e] += bf2f(vf[e]);
            xg[e] += bf2f(vg[e]); xc[e] += bf2f(vc[e]);
        }
    }

    const float* po = states + BH;
    floatx4 pov[2];
    pov[0] = *(const floatx4*)&po[idx];
    pov[1] = *(const floatx4*)&po[idx + 4];

    floatx4 vcv[2], vsv[2];
    #pragma unroll
    for (int q = 0; q < 2; q++)
        #pragma unroll
        for (int j = 0; j < 4; j++) {
            int e = q*4 + j;
            float c = fsig(xf[e]) * pov[q][j] + fsig(xi[e]) * ftanh(xc[e]);
            vcv[q][j] = c;
            vsv[q][j] = fsig(xg[e]) * ftanh(c);
        }
    #pragma unroll
    for (int q = 0; q < 2; q++) {
        *(floatx4*)&out[idx + q*4]        = vcv[q];
        *(floatx4*)&out[BH + idx + q*4]   = vsv[q];
        *(floatx4*)&out[2*BH + idx + q*4] = vcv[q];
    }
}

extern "C" void kernel_launch(void* const* d_in, const int* in_sizes, int n_in,
                              void* d_out, int out_size, void* d_ws, size_t ws_size,
                              hipStream_t stream) {
    const float* inputs = (const float*)d_in[0];
    const float* states = (const float*)d_in[1];
    const float* Wi = (const float*)d_in[2];
    const float* Ui = (const float*)d_in[3];
    const float* bi = (const float*)d_in[4];
    const float* Wf = (const float*)d_in[5];
    const float* Uf = (const float*)d_in[6];
    const float* bf = (const float*)d_in[7];
    const float* Wg = (const float*)d_in[8];
    const float* Ug = (const float*)d_in[9];
    const float* bg = (const float*)d_in[10];
    const float* Wc = (const float*)d_in[11];
    const float* Uc = (const float*)d_in[12];
    const float* bc = (const float*)d_in[13];
    float* out = (float*)d_out;

    const size_t need = (WT_ELEMS + AB_ELEMS + 4 * PPLANE) * 2;   // 100 MiB
    if (ws_size >= need) {
        unsigned short* Wt = (unsigned short*)d_ws;
        unsigned short* Ab = Wt + WT_ELEMS;
        unsigned short* P  = Ab + AB_ELEMS;
        prep<<<3072, 256, 0, stream>>>(inputs, states, Wi, Ui, Wf, Uf,
                                       Wg, Ug, Wc, Uc, Wt, Ab);
        gemm_lds<<<dim3(64, 4, 4), 256, 0, stream>>>(Wt, Ab, P);
        combine_kernel<<<BH / (8 * 256), 256, 0, stream>>>(out, P, states,
                                                           bi, bf, bg, bc, 4);
    } else {
        unsigned short* P = (unsigned short*)d_ws;
        const int nz = (ws_size >= 4 * PLANE_BYTES) ? 4 : 2;
        const int KB = 4096 / nz;
        dim3 grid(64, 4, nz);
        gemm_tile<<<grid, 256, 0, stream>>>(inputs, states, Wi, Ui, Wf, Uf,
                                            Wg, Ug, Wc, Uc, P, KB);
        combine_kernel<<<BH / (8 * 256), 256, 0, stream>>>(out, P, states,
                                                           bi, bf, bg, bc, nz);
    }
}